// Round 2
// baseline (1653.612 us; speedup 1.0000x reference)
//
#include <hip/hip_runtime.h>
#include <math.h>

#define D 128
#define MAXNORM 0.996f            // (1 - 4e-3)/sqrt(c), c = 1
#define MINNORM 1e-15f
#define ATCLAMP (1.0f - 1e-7f)

#define CHUNK 2048                // edges per ks1 block (8 per thread)
#define BSH   7                   // 128 nodes per bucket
#define MAXNB 1024                // supports N <= 131072 (problem: N = 100000)

typedef unsigned int   u32;
typedef unsigned short u16;

typedef __attribute__((ext_vector_type(8))) short bf16x8;
typedef __attribute__((ext_vector_type(4))) float f32x4;

__device__ __forceinline__ float wsum(float v) {
#pragma unroll
  for (int m = 32; m; m >>= 1) v += __shfl_xor(v, m);
  return v;
}
// 16-lane reduction (stays within a lane&48 group) — matches MFMA C-layout rows
__device__ __forceinline__ float rsum16(float v) {
#pragma unroll
  for (int m = 1; m <= 8; m <<= 1) v += __shfl_xor(v, m);
  return v;
}

__device__ __forceinline__ float frcp(float x) { return __builtin_amdgcn_rcpf(x); }

// fast artanh for x in [0, 1-1e-7]
__device__ __forceinline__ float fast_artanh(float x) {
  x = fminf(x, ATCLAMP);
  return 0.5f * __logf((1.0f + x) * frcp(1.0f - x));
}
// fast tanh for z >= 0
__device__ __forceinline__ float fast_tanh(float z) {
  float t = __expf(-2.0f * z);
  return (1.0f - t) * frcp(1.0f + t);
}

__device__ __forceinline__ float bflo(u32 u) { return __uint_as_float(u << 16); }
__device__ __forceinline__ float bfhi(u32 u) { return __uint_as_float(u & 0xffff0000u); }
__device__ __forceinline__ u16 f2bf(float f) {            // RNE f32 -> bf16
  u32 u = __float_as_uint(f);
  return (u16)((u + 0x7fffu + ((u >> 16) & 1u)) >> 16);
}
__device__ __forceinline__ float bf2f(u16 h) { return __uint_as_float(((u32)h) << 16); }

union U4B8 { uint4 u; bf16x8 b; };
__device__ __forceinline__ bf16x8 as_b8(uint4 v) { U4B8 c; c.u = v; return c.b; }

// ---- runtime dtype detection (wave-uniform; call before any divergence) ----
__device__ __forceinline__ bool detect_bf16(const u32* p) {
  float lo = fabsf(bflo(p[threadIdx.x & 63]));
  return (bool)__all(lo < 1.0f);
}
__device__ __forceinline__ bool detect_i64(const int* p) {
  return (bool)__all(p[2 * (threadIdx.x & 63) + 1] == 0);
}

// ====== K1: MFMA mobius_matvec + proj + mobius_add(bias) + proj + logmap0 ======
// (unchanged from previous round — verified) One 16x128 output tile per wave via
// mfma_f32_16x16x32_bf16; W staged in LDS in B-fragment order; fp32 path uses
// bf16x3 split. C layout (m89-verified): col = lane&15, row = (lane>>4)*4 + reg.
template<bool BF>
__device__ __forceinline__ void k1_body(const void* xv, const void* Wv,
                                        const void* bv, u16* xt, int N,
                                        uint4* Wh, uint4* Wl) {
  const int tid  = threadIdx.x;
  const int lane = tid & 63;
  const int wid  = tid >> 6;
  const int qg   = lane >> 4;   // k-block group 0..3
  const int lc   = lane & 15;   // col within 16-wide tile

  for (int slot = tid; slot < 2048; slot += 256) {
    const int l = slot & 63, frag = slot >> 6;
    const int t = frag >> 2, ks = frag & 3;
    const int j  = (l & 15) + 16 * t;
    const int k0 = 32 * ks + 8 * (l >> 4);
    if (BF) {
      Wh[slot] = ((const uint4*)Wv)[j * 16 + (k0 >> 3)];
    } else {
      const float* Wf = (const float*)Wv;
      float4 f0 = *(const float4*)(Wf + (size_t)j * D + k0);
      float4 f1 = *(const float4*)(Wf + (size_t)j * D + k0 + 4);
      float f[8] = {f0.x, f0.y, f0.z, f0.w, f1.x, f1.y, f1.z, f1.w};
      u32 hw[4], lw[4];
#pragma unroll
      for (int i = 0; i < 4; ++i) {
        u16 h0 = f2bf(f[2*i]),  h1 = f2bf(f[2*i+1]);
        u16 l0 = f2bf(f[2*i]   - bf2f(h0));
        u16 l1 = f2bf(f[2*i+1] - bf2f(h1));
        hw[i] = (u32)h0 | ((u32)h1 << 16);
        lw[i] = (u32)l0 | ((u32)l1 << 16);
      }
      Wh[slot] = make_uint4(hw[0], hw[1], hw[2], hw[3]);
      Wl[slot] = make_uint4(lw[0], lw[1], lw[2], lw[3]);
    }
  }

  float bfr[8];
  float nb2 = 0.f;
#pragma unroll
  for (int t = 0; t < 8; ++t) {
    float v = BF ? bf2f(((const u16*)bv)[lc + 16 * t])
                 : ((const float*)bv)[lc + 16 * t];
    bfr[t] = v; nb2 += v * v;
  }
  nb2 = rsum16(nb2);
  float y2;
  {
    float nb = fmaxf(sqrtf(nb2), MINNORM);
    float s  = fast_tanh(nb) * frcp(nb);
    float n1 = s * nb;
    if (n1 > MAXNORM) s *= MAXNORM * frcp(n1);
#pragma unroll
    for (int t = 0; t < 8; ++t) bfr[t] *= s;
    y2 = s * s * nb2;
  }
  const bool bias_zero = (y2 == 0.0f);

  __syncthreads();

  const int tile  = blockIdx.x * 4 + wid;
  const int rbase = tile * 16;
  if (rbase >= N) return;

  int rowA = rbase + lc; if (rowA >= N) rowA = N - 1;
  uint4 Ah[4], Al[4];
  float xn2 = 0.f;
  if (BF) {
    const uint4* xr = (const uint4*)((const u16*)xv + (size_t)rowA * D);
#pragma unroll
    for (int ks = 0; ks < 4; ++ks) {
      uint4 v = xr[4 * ks + qg];
      Ah[ks] = v;
      float a0 = bflo(v.x), a1 = bfhi(v.x), a2 = bflo(v.y), a3 = bfhi(v.y);
      float a4 = bflo(v.z), a5 = bfhi(v.z), a6 = bflo(v.w), a7 = bfhi(v.w);
      xn2 += a0*a0 + a1*a1 + a2*a2 + a3*a3 + a4*a4 + a5*a5 + a6*a6 + a7*a7;
    }
  } else {
    const float4* xr = (const float4*)((const float*)xv + (size_t)rowA * D);
#pragma unroll
    for (int ks = 0; ks < 4; ++ks) {
      float4 f0 = xr[8 * ks + 2 * qg], f1 = xr[8 * ks + 2 * qg + 1];
      float f[8] = {f0.x, f0.y, f0.z, f0.w, f1.x, f1.y, f1.z, f1.w};
      u32 hw[4], lw[4];
#pragma unroll
      for (int i = 0; i < 4; ++i) {
        u16 h0 = f2bf(f[2*i]),  h1 = f2bf(f[2*i+1]);
        u16 l0 = f2bf(f[2*i]   - bf2f(h0));
        u16 l1 = f2bf(f[2*i+1] - bf2f(h1));
        hw[i] = (u32)h0 | ((u32)h1 << 16);
        lw[i] = (u32)l0 | ((u32)l1 << 16);
        xn2 += f[2*i] * f[2*i] + f[2*i+1] * f[2*i+1];
      }
      Ah[ks] = make_uint4(hw[0], hw[1], hw[2], hw[3]);
      Al[ks] = make_uint4(lw[0], lw[1], lw[2], lw[3]);
    }
  }
  xn2 += __shfl_xor(xn2, 16);
  xn2 += __shfl_xor(xn2, 32);

  f32x4 acc[8];
  const f32x4 zero = {0.f, 0.f, 0.f, 0.f};
#pragma unroll
  for (int t = 0; t < 8; ++t) acc[t] = zero;
#pragma unroll
  for (int ks = 0; ks < 4; ++ks) {
    bf16x8 a = as_b8(Ah[ks]);
    bf16x8 al;
    if (!BF) al = as_b8(Al[ks]);
#pragma unroll
    for (int t = 0; t < 8; ++t) {
      const int idx = (t * 4 + ks) * 64 + lane;
      bf16x8 bh = as_b8(Wh[idx]);
      acc[t] = __builtin_amdgcn_mfma_f32_16x16x32_bf16(a, bh, acc[t], 0, 0, 0);
      if (!BF) {
        bf16x8 bl = as_b8(Wl[idx]);
        acc[t] = __builtin_amdgcn_mfma_f32_16x16x32_bf16(al, bh, acc[t], 0, 0, 0);
        acc[t] = __builtin_amdgcn_mfma_f32_16x16x32_bf16(a,  bl, acc[t], 0, 0, 0);
      }
    }
  }

#pragma unroll
  for (int q = 0; q < 4; ++q) {
    const int row_off = qg * 4 + q;
    const int row = rbase + row_off;
    float xnq = fmaxf(sqrtf(__shfl(xn2, row_off)), MINNORM);
    float s2 = 0.f;
#pragma unroll
    for (int t = 0; t < 8; ++t) { float v = acc[t][q]; s2 += v * v; }
    s2 = rsum16(s2);
    float mxn = fmaxf(sqrtf(s2), MINNORM);
    float r = fast_tanh(mxn * frcp(xnq) * fast_artanh(xnq)) * frcp(mxn);
    float pn = r * mxn;
    if (pn > MAXNORM) { r *= MAXNORM * frcp(pn); pn = MAXNORM; }
    float h[8];
    float hn;
    if (bias_zero) {
#pragma unroll
      for (int t = 0; t < 8; ++t) h[t] = r * acc[t][q];
      hn = pn;
    } else {
      float xy = 0.f;
#pragma unroll
      for (int t = 0; t < 8; ++t) { h[t] = r * acc[t][q]; xy += h[t] * bfr[t]; }
      xy = rsum16(xy);
      float x2 = pn * pn;
      float ca = 1.f + 2.f * xy + y2;
      float cb = 1.f - x2;
      float id = frcp(fmaxf(1.f + 2.f * xy + x2 * y2, MINNORM));
      float s3 = 0.f;
#pragma unroll
      for (int t = 0; t < 8; ++t) { h[t] = (ca * h[t] + cb * bfr[t]) * id; s3 += h[t] * h[t]; }
      hn = fmaxf(sqrtf(rsum16(s3)), MINNORM);
    }
    float ps = (hn > MAXNORM) ? (MAXNORM * frcp(hn)) : 1.f;
    float np = fmaxf(hn * ps, MINNORM);
    float tsc = fast_artanh(np) * frcp(np) * ps;
    if (row < N) {
      u16* xo = xt + (size_t)row * D + lc;
#pragma unroll
      for (int t = 0; t < 8; ++t) xo[16 * t] = f2bf(tsc * h[t]);
    }
  }
}

extern "C" __global__ __launch_bounds__(256)
void OriginHyperbolicGraphConvolution_38628935860614_kernel(
    const void* x, const void* W, const void* b, u16* xt, int N) {
  __shared__ uint4 Wh[2048];   // 32 KB
  __shared__ uint4 Wl[2048];   // 32 KB (fp32 input path only)
  if (detect_bf16((const u32*)x)) k1_body<true >(x, W, b, xt, N, Wh, Wl);
  else                            k1_body<false>(x, W, b, xt, N, Wh, Wl);
}

// ====== ks1: chunk-local counting sort by coarse bucket (dst >> BSH) ======
// Block = 256 threads = 2048 edges. LDS sort, then SEQUENTIAL coalesced write of
// the chunk's records (full 64B lines -> no write amplification), plus a u16
// per-chunk bucket-offset table. Record: x = src(17b) | dstin(7b)<<17, y = w f32.
extern "C" __global__ __launch_bounds__(256) void ks1(
    const int* ei, const void* ew, uint2* ebuck, u16* soffs, int E, int N, int nb) {
  __shared__ int  hist[MAXNB];      // 4 KB
  __shared__ int  psum[256];        // 1 KB
  __shared__ uint2 recs[CHUNK];     // 16 KB
  const bool i64 = detect_i64(ei);
  const bool bf  = detect_bf16((const u32*)ew);
  const int tid   = threadIdx.x;
  const int cbase = blockIdx.x * CHUNK;

  for (int i = tid; i < MAXNB; i += 256) hist[i] = 0;
  __syncthreads();

  int  bkt[8], rank[8];
  u32  px[8], wb[8];
  bool val[8];
#pragma unroll
  for (int r = 0; r < 8; ++r) {
    const int e = cbase + r * 256 + tid;
    val[r] = false;
    if (e < E) {
      int dst, src;
      if (i64) { dst = ei[2 * (size_t)e]; src = ei[2 * ((size_t)E + e)]; }
      else     { dst = ei[e];             src = ei[(size_t)E + e]; }
      if ((unsigned)dst < (unsigned)N && (unsigned)src < (unsigned)N) {
        val[r] = true;
        bkt[r] = dst >> BSH;
        px[r]  = (u32)src | ((u32)(dst & ((1 << BSH) - 1)) << 17);
        float w;
        if (bf) w = bf2f(((const u16*)ew)[e]); else w = ((const float*)ew)[e];
        wb[r] = __float_as_uint(w);
        rank[r] = atomicAdd(&hist[bkt[r]], 1);
      }
    }
  }
  __syncthreads();

  // exclusive scan of hist[0..MAXNB) with 256 threads x 4 bins each
  const int g0 = tid * 4;
  int loc[4], tsum = 0;
#pragma unroll
  for (int i = 0; i < 4; ++i) { loc[i] = tsum; tsum += hist[g0 + i]; }
  psum[tid] = tsum; __syncthreads();
#pragma unroll
  for (int off = 1; off < 256; off <<= 1) {
    int t = (tid >= off) ? psum[tid - off] : 0;
    __syncthreads();
    psum[tid] += t;
    __syncthreads();
  }
  const int excl = psum[tid] - tsum;
  const int vcnt = psum[255];
  int bb[4];
#pragma unroll
  for (int i = 0; i < 4; ++i) { bb[i] = excl + loc[i]; hist[g0 + i] = bb[i]; }
  __syncthreads();

#pragma unroll
  for (int r = 0; r < 8; ++r)
    if (val[r]) recs[hist[bkt[r]] + rank[r]] = make_uint2(px[r], wb[r]);
  __syncthreads();

  for (int i = tid; i < vcnt; i += 256)
    ebuck[(size_t)cbase + i] = recs[i];
  u16* so = soffs + (size_t)blockIdx.x * (nb + 1);
#pragma unroll
  for (int i = 0; i < 4; ++i) if (g0 + i < nb) so[g0 + i] = (u16)bb[i];
  if (tid == 0) so[nb] = (u16)vcnt;
}

// ====== kagg2: bucket-owned aggregate + fused finalize ======
// One block per 128-node bucket; f32 accumulator in LDS (64 KB). Walks its
// segment in each chunk, 4 chunk-streams interleaved per wave (4 gathers in
// flight). ds_add_f32 into split layout: feature 2l at [n][l], 2l+1 at
// [n][64+l] — stride-4B across lanes -> 2-way bank alias = free.
extern "C" __global__ __launch_bounds__(256) void kagg2(
    const uint2* ebuck, const u16* soffs, const u16* xt,
    void* out, const void* xdet, int N, int nb, int nchunks) {
  __shared__ float sup[128 * 128];          // 64 KB
  const bool bf = detect_bf16((const u32*)xdet);
  const int tid = threadIdx.x;
  const int lane = tid & 63, wid = tid >> 6;
  const int b = blockIdx.x;
  const int node0 = b << BSH;
  {
    const f32x4 z = {0.f, 0.f, 0.f, 0.f};
    for (int i = tid * 4; i < 128 * 128; i += 1024) *(f32x4*)&sup[i] = z;
  }
  __syncthreads();

  const u32* xtw = (const u32*)xt;
  for (int c0 = wid; c0 < nchunks; c0 += 16) {
    int m[4], mk[4];
    const uint2* seg[4];
#pragma unroll
    for (int k = 0; k < 4; ++k) {
      const int c = c0 + 4 * k;
      if (c < nchunks) {
        const u16* so = soffs + (size_t)c * (nb + 1) + b;
        const int a = so[0], e = so[1];
        seg[k] = ebuck + (size_t)c * CHUNK + a;
        m[k] = e - a;
      } else m[k] = 0;
      mk[k] = min(m[k], 64);
    }
    uint2 ed[4];
#pragma unroll
    for (int k = 0; k < 4; ++k) {
      ed[k] = make_uint2(0u, 0u);
      if (lane < mk[k]) ed[k] = seg[k][lane];
    }
    const int mm = max(max(mk[0], mk[1]), max(mk[2], mk[3]));
    for (int j = 0; j < mm; ++j) {
      u32 p[4], u[4]; float w[4];
#pragma unroll
      for (int k = 0; k < 4; ++k) {
        p[k] = __shfl(ed[k].x, j);
        w[k] = __uint_as_float(__shfl(ed[k].y, j));
        if (j < mk[k]) u[k] = xtw[(size_t)(p[k] & 0x1FFFFu) * 64 + lane];
      }
#pragma unroll
      for (int k = 0; k < 4; ++k) if (j < mk[k]) {
        const int din = (p[k] >> 17) & 127;
        atomicAdd(&sup[din * 128 + lane],      w[k] * bflo(u[k]));
        atomicAdd(&sup[din * 128 + 64 + lane], w[k] * bfhi(u[k]));
      }
    }
    // rare path: segment longer than 64 records
#pragma unroll
    for (int k = 0; k < 4; ++k) {
      for (int bs = 64; bs < m[k]; bs += 64) {
        const int m2 = min(64, m[k] - bs);
        uint2 e2 = make_uint2(0u, 0u);
        if (lane < m2) e2 = seg[k][bs + lane];
        for (int j = 0; j < m2; ++j) {
          const u32 pp = __shfl(e2.x, j);
          const float ww = __uint_as_float(__shfl(e2.y, j));
          const u32 uu = xtw[(size_t)(pp & 0x1FFFFu) * 64 + lane];
          const int din = (pp >> 17) & 127;
          atomicAdd(&sup[din * 128 + lane],      ww * bflo(uu));
          atomicAdd(&sup[din * 128 + 64 + lane], ww * bfhi(uu));
        }
      }
    }
  }
  __syncthreads();

  // finalize: expmap0 -> proj -> logmap0 -> relu -> expmap0 -> proj
  for (int n = wid; n < 128; n += 4) {
    const int node = node0 + n;
    if (node >= N) continue;
    const float a0 = sup[n * 128 + lane];        // feature 2*lane
    const float a1 = sup[n * 128 + 64 + lane];   // feature 2*lane+1
    float nn0 = fmaxf(sqrtf(wsum(a0 * a0 + a1 * a1)), MINNORM);
    float tn = fast_tanh(nn0);
    float mm = tn * frcp(nn0);
    if (tn > MAXNORM) { mm *= MAXNORM * frcp(tn); tn = MAXNORM; }
    float nn = fmaxf(tn, MINNORM);
    mm *= fast_artanh(nn) * frcp(nn);
    float tA = fmaxf(mm * a0, 0.f), tB = fmaxf(mm * a1, 0.f);
    float nr = fmaxf(sqrtf(wsum(tA * tA + tB * tB)), MINNORM);
    float t2 = fast_tanh(nr);
    float m2 = t2 * frcp(nr);
    if (t2 > MAXNORM) m2 *= MAXNORM * frcp(t2);
    float oA = m2 * tA, oB = m2 * tB;
    if (bf) {
      u32 o = ((u32)f2bf(oA)) | (((u32)f2bf(oB)) << 16);
      ((u32*)out)[(size_t)node * 64 + lane] = o;
    } else {
      ((float2*)out)[(size_t)node * 64 + lane] = make_float2(oA, oB);
    }
  }
}

extern "C" void kernel_launch(void* const* d_in, const int* in_sizes, int n_in,
                              void* d_out, int out_size, void* d_ws, size_t ws_size,
                              hipStream_t stream) {
  const void* x    = d_in[0];
  const void* W    = d_in[1];
  const void* bias = d_in[2];
  const int*  ei   = (const int*)d_in[3];
  const void* ew   = d_in[4];
  const int N = in_sizes[0] / D;
  const int E = in_sizes[4];
  const int nchunks = (E + CHUNK - 1) / CHUNK;
  const int nb      = (N + (1 << BSH) - 1) >> BSH;

  char* ws = (char*)d_ws;
  size_t off = 0;
  auto carve = [&](size_t bytes) { char* p = ws + off; off = (off + bytes + 255) & ~(size_t)255; return p; };
  u16*   xt    = (u16*)  carve((size_t)N * D * sizeof(u16));               // 25.6 MB
  uint2* ebuck = (uint2*)carve((size_t)nchunks * CHUNK * sizeof(uint2));   // 12.8 MB
  u16*   soffs = (u16*)  carve((size_t)nchunks * (nb + 1) * sizeof(u16));  // 1.2 MB

  OriginHyperbolicGraphConvolution_38628935860614_kernel<<<(N + 63) / 64, 256, 0, stream>>>(
      x, W, bias, xt, N);
  ks1  <<<nchunks, 256, 0, stream>>>(ei, ew, ebuck, soffs, E, N, nb);
  kagg2<<<nb,      256, 0, stream>>>(ebuck, soffs, xt, d_out, x, N, nb, nchunks);
}

// Round 3
// 1588.875 us; speedup vs baseline: 1.0407x; 1.0407x over previous
//
#include <hip/hip_runtime.h>
#include <math.h>

#define D 128
#define MAXNORM 0.996f            // (1 - 4e-3)/sqrt(c), c = 1
#define MINNORM 1e-15f
#define ATCLAMP (1.0f - 1e-7f)

#define CHUNK 2048                // edges per sort block (8 per thread)
#define BSH   7                   // 128 nodes per bucket
#define MAXNB 1024                // supports N <= 131072 (problem: N = 100000)

typedef unsigned int   u32;
typedef unsigned short u16;

typedef __attribute__((ext_vector_type(8))) short bf16x8;
typedef __attribute__((ext_vector_type(4))) float f32x4;

__device__ __forceinline__ float wsum(float v) {
#pragma unroll
  for (int m = 32; m; m >>= 1) v += __shfl_xor(v, m);
  return v;
}
// 16-lane reduction (stays within a lane&48 group) — matches MFMA C-layout rows
__device__ __forceinline__ float rsum16(float v) {
#pragma unroll
  for (int m = 1; m <= 8; m <<= 1) v += __shfl_xor(v, m);
  return v;
}

__device__ __forceinline__ float frcp(float x) { return __builtin_amdgcn_rcpf(x); }

// fast artanh for x in [0, 1-1e-7]
__device__ __forceinline__ float fast_artanh(float x) {
  x = fminf(x, ATCLAMP);
  return 0.5f * __logf((1.0f + x) * frcp(1.0f - x));
}
// fast tanh for z >= 0
__device__ __forceinline__ float fast_tanh(float z) {
  float t = __expf(-2.0f * z);
  return (1.0f - t) * frcp(1.0f + t);
}

__device__ __forceinline__ float bflo(u32 u) { return __uint_as_float(u << 16); }
__device__ __forceinline__ float bfhi(u32 u) { return __uint_as_float(u & 0xffff0000u); }
__device__ __forceinline__ u16 f2bf(float f) {            // RNE f32 -> bf16
  u32 u = __float_as_uint(f);
  return (u16)((u + 0x7fffu + ((u >> 16) & 1u)) >> 16);
}
__device__ __forceinline__ float bf2f(u16 h) { return __uint_as_float(((u32)h) << 16); }

union U4B8 { uint4 u; bf16x8 b; };
__device__ __forceinline__ bf16x8 as_b8(uint4 v) { U4B8 c; c.u = v; return c.b; }

// ---- runtime dtype detection (wave-uniform; call before any divergence) ----
__device__ __forceinline__ bool detect_bf16(const u32* p) {
  float lo = fabsf(bflo(p[threadIdx.x & 63]));
  return (bool)__all(lo < 1.0f);
}
__device__ __forceinline__ bool detect_i64(const int* p) {
  return (bool)__all(p[2 * (threadIdx.x & 63) + 1] == 0);
}

// ====== K1: MFMA mobius_matvec + proj + mobius_add(bias) + proj + logmap0 ======
// (verified in rounds 1-2) One 16x128 output tile per wave via
// mfma_f32_16x16x32_bf16; W staged in LDS in B-fragment order; fp32 path uses
// bf16x3 split. C layout (m89-verified): col = lane&15, row = (lane>>4)*4 + reg.
template<bool BF>
__device__ __forceinline__ void k1_body(const void* xv, const void* Wv,
                                        const void* bv, u16* xt, int N,
                                        uint4* Wh, uint4* Wl) {
  const int tid  = threadIdx.x;
  const int lane = tid & 63;
  const int wid  = tid >> 6;
  const int qg   = lane >> 4;   // k-block group 0..3
  const int lc   = lane & 15;   // col within 16-wide tile

  for (int slot = tid; slot < 2048; slot += 256) {
    const int l = slot & 63, frag = slot >> 6;
    const int t = frag >> 2, ks = frag & 3;
    const int j  = (l & 15) + 16 * t;
    const int k0 = 32 * ks + 8 * (l >> 4);
    if (BF) {
      Wh[slot] = ((const uint4*)Wv)[j * 16 + (k0 >> 3)];
    } else {
      const float* Wf = (const float*)Wv;
      float4 f0 = *(const float4*)(Wf + (size_t)j * D + k0);
      float4 f1 = *(const float4*)(Wf + (size_t)j * D + k0 + 4);
      float f[8] = {f0.x, f0.y, f0.z, f0.w, f1.x, f1.y, f1.z, f1.w};
      u32 hw[4], lw[4];
#pragma unroll
      for (int i = 0; i < 4; ++i) {
        u16 h0 = f2bf(f[2*i]),  h1 = f2bf(f[2*i+1]);
        u16 l0 = f2bf(f[2*i]   - bf2f(h0));
        u16 l1 = f2bf(f[2*i+1] - bf2f(h1));
        hw[i] = (u32)h0 | ((u32)h1 << 16);
        lw[i] = (u32)l0 | ((u32)l1 << 16);
      }
      Wh[slot] = make_uint4(hw[0], hw[1], hw[2], hw[3]);
      Wl[slot] = make_uint4(lw[0], lw[1], lw[2], lw[3]);
    }
  }

  float bfr[8];
  float nb2 = 0.f;
#pragma unroll
  for (int t = 0; t < 8; ++t) {
    float v = BF ? bf2f(((const u16*)bv)[lc + 16 * t])
                 : ((const float*)bv)[lc + 16 * t];
    bfr[t] = v; nb2 += v * v;
  }
  nb2 = rsum16(nb2);
  float y2;
  {
    float nb = fmaxf(sqrtf(nb2), MINNORM);
    float s  = fast_tanh(nb) * frcp(nb);
    float n1 = s * nb;
    if (n1 > MAXNORM) s *= MAXNORM * frcp(n1);
#pragma unroll
    for (int t = 0; t < 8; ++t) bfr[t] *= s;
    y2 = s * s * nb2;
  }
  const bool bias_zero = (y2 == 0.0f);

  __syncthreads();

  const int tile  = blockIdx.x * 4 + wid;
  const int rbase = tile * 16;
  if (rbase >= N) return;

  int rowA = rbase + lc; if (rowA >= N) rowA = N - 1;
  uint4 Ah[4], Al[4];
  float xn2 = 0.f;
  if (BF) {
    const uint4* xr = (const uint4*)((const u16*)xv + (size_t)rowA * D);
#pragma unroll
    for (int ks = 0; ks < 4; ++ks) {
      uint4 v = xr[4 * ks + qg];
      Ah[ks] = v;
      float a0 = bflo(v.x), a1 = bfhi(v.x), a2 = bflo(v.y), a3 = bfhi(v.y);
      float a4 = bflo(v.z), a5 = bfhi(v.z), a6 = bflo(v.w), a7 = bfhi(v.w);
      xn2 += a0*a0 + a1*a1 + a2*a2 + a3*a3 + a4*a4 + a5*a5 + a6*a6 + a7*a7;
    }
  } else {
    const float4* xr = (const float4*)((const float*)xv + (size_t)rowA * D);
#pragma unroll
    for (int ks = 0; ks < 4; ++ks) {
      float4 f0 = xr[8 * ks + 2 * qg], f1 = xr[8 * ks + 2 * qg + 1];
      float f[8] = {f0.x, f0.y, f0.z, f0.w, f1.x, f1.y, f1.z, f1.w};
      u32 hw[4], lw[4];
#pragma unroll
      for (int i = 0; i < 4; ++i) {
        u16 h0 = f2bf(f[2*i]),  h1 = f2bf(f[2*i+1]);
        u16 l0 = f2bf(f[2*i]   - bf2f(h0));
        u16 l1 = f2bf(f[2*i+1] - bf2f(h1));
        hw[i] = (u32)h0 | ((u32)h1 << 16);
        lw[i] = (u32)l0 | ((u32)l1 << 16);
        xn2 += f[2*i] * f[2*i] + f[2*i+1] * f[2*i+1];
      }
      Ah[ks] = make_uint4(hw[0], hw[1], hw[2], hw[3]);
      Al[ks] = make_uint4(lw[0], lw[1], lw[2], lw[3]);
    }
  }
  xn2 += __shfl_xor(xn2, 16);
  xn2 += __shfl_xor(xn2, 32);

  f32x4 acc[8];
  const f32x4 zero = {0.f, 0.f, 0.f, 0.f};
#pragma unroll
  for (int t = 0; t < 8; ++t) acc[t] = zero;
#pragma unroll
  for (int ks = 0; ks < 4; ++ks) {
    bf16x8 a = as_b8(Ah[ks]);
    bf16x8 al;
    if (!BF) al = as_b8(Al[ks]);
#pragma unroll
    for (int t = 0; t < 8; ++t) {
      const int idx = (t * 4 + ks) * 64 + lane;
      bf16x8 bh = as_b8(Wh[idx]);
      acc[t] = __builtin_amdgcn_mfma_f32_16x16x32_bf16(a, bh, acc[t], 0, 0, 0);
      if (!BF) {
        bf16x8 bl = as_b8(Wl[idx]);
        acc[t] = __builtin_amdgcn_mfma_f32_16x16x32_bf16(al, bh, acc[t], 0, 0, 0);
        acc[t] = __builtin_amdgcn_mfma_f32_16x16x32_bf16(a,  bl, acc[t], 0, 0, 0);
      }
    }
  }

#pragma unroll
  for (int q = 0; q < 4; ++q) {
    const int row_off = qg * 4 + q;
    const int row = rbase + row_off;
    float xnq = fmaxf(sqrtf(__shfl(xn2, row_off)), MINNORM);
    float s2 = 0.f;
#pragma unroll
    for (int t = 0; t < 8; ++t) { float v = acc[t][q]; s2 += v * v; }
    s2 = rsum16(s2);
    float mxn = fmaxf(sqrtf(s2), MINNORM);
    float r = fast_tanh(mxn * frcp(xnq) * fast_artanh(xnq)) * frcp(mxn);
    float pn = r * mxn;
    if (pn > MAXNORM) { r *= MAXNORM * frcp(pn); pn = MAXNORM; }
    float h[8];
    float hn;
    if (bias_zero) {
#pragma unroll
      for (int t = 0; t < 8; ++t) h[t] = r * acc[t][q];
      hn = pn;
    } else {
      float xy = 0.f;
#pragma unroll
      for (int t = 0; t < 8; ++t) { h[t] = r * acc[t][q]; xy += h[t] * bfr[t]; }
      xy = rsum16(xy);
      float x2 = pn * pn;
      float ca = 1.f + 2.f * xy + y2;
      float cb = 1.f - x2;
      float id = frcp(fmaxf(1.f + 2.f * xy + x2 * y2, MINNORM));
      float s3 = 0.f;
#pragma unroll
      for (int t = 0; t < 8; ++t) { h[t] = (ca * h[t] + cb * bfr[t]) * id; s3 += h[t] * h[t]; }
      hn = fmaxf(sqrtf(rsum16(s3)), MINNORM);
    }
    float ps = (hn > MAXNORM) ? (MAXNORM * frcp(hn)) : 1.f;
    float np = fmaxf(hn * ps, MINNORM);
    float tsc = fast_artanh(np) * frcp(np) * ps;
    if (row < N) {
      u16* xo = xt + (size_t)row * D + lc;
#pragma unroll
      for (int t = 0; t < 8; ++t) xo[16 * t] = f2bf(tsc * h[t]);
    }
  }
}

extern "C" __global__ __launch_bounds__(256)
void OriginHyperbolicGraphConvolution_38628935860614_kernel(
    const void* x, const void* W, const void* b, u16* xt, int N) {
  __shared__ uint4 Wh[2048];   // 32 KB
  __shared__ uint4 Wl[2048];   // 32 KB (fp32 input path only)
  if (detect_bf16((const u32*)x)) k1_body<true >(x, W, b, xt, N, Wh, Wl);
  else                            k1_body<false>(x, W, b, xt, N, Wh, Wl);
}

// ====== ks1a: per-chunk bucket histogram -> u16 count row (coalesced) ======
extern "C" __global__ __launch_bounds__(256) void ks1a(
    const int* ei, u16* cnt, int E, int N, int nb) {
  __shared__ int hist[MAXNB];     // 4 KB
  const bool i64 = detect_i64(ei);
  const int tid = threadIdx.x;
  const int cbase = blockIdx.x * CHUNK;
  for (int i = tid; i < MAXNB; i += 256) hist[i] = 0;
  __syncthreads();
#pragma unroll
  for (int r = 0; r < 8; ++r) {
    const int e = cbase + r * 256 + tid;
    if (e < E) {
      int dst, src;
      if (i64) { dst = ei[2 * (size_t)e]; src = ei[2 * ((size_t)E + e)]; }
      else     { dst = ei[e];             src = ei[(size_t)E + e]; }
      if ((unsigned)dst < (unsigned)N && (unsigned)src < (unsigned)N)
        atomicAdd(&hist[dst >> BSH], 1);
    }
  }
  __syncthreads();
  u16* row = cnt + (size_t)blockIdx.x * nb;
  for (int b = tid; b < nb; b += 256) row[b] = (u16)hist[b];
}

// ====== ks2sum: per-bucket total = column sum over chunks (cnt is L2-resident) ======
extern "C" __global__ __launch_bounds__(256) void ks2sum(
    const u16* cnt, int* btot, int nb, int nchunks) {
  __shared__ int red[256];
  const int b = blockIdx.x, tid = threadIdx.x;
  int s = 0;
  for (int c = tid; c < nchunks; c += 256) s += cnt[(size_t)c * nb + b];
  red[tid] = s; __syncthreads();
#pragma unroll
  for (int off = 128; off; off >>= 1) {
    if (tid < off) red[tid] += red[tid + off];
    __syncthreads();
  }
  if (tid == 0) btot[b] = red[0];
}

// ====== ks2scan: bucket bases + cursor init (nb <= 1024) ======
extern "C" __global__ __launch_bounds__(1024) void ks2scan(
    const int* btot, int* bbase, int* cursor, int nb) {
  __shared__ int sc[1024];
  const int t = threadIdx.x;
  int v = (t < nb) ? btot[t] : 0;
  sc[t] = v; __syncthreads();
#pragma unroll
  for (int off = 1; off < 1024; off <<= 1) {
    int u = (t >= off) ? sc[t - off] : 0;
    __syncthreads();
    sc[t] += u;
    __syncthreads();
  }
  if (t < nb) { int o = sc[t] - v; bbase[t] = o; cursor[t] = o; }
  if (t == 1023) bbase[nb] = sc[1023];
}

// ====== ks1b: chunk-local counting sort + run-claim scatter to bucket-contiguous esrt ======
// Per (chunk,bucket) run of ~2.6 records: ONE global atomicAdd claims a
// contiguous destination run; records then written i->dest piecewise-contiguous
// (~3x line amplification on 12.8 MB, vs 8x of the old per-record scatter).
extern "C" __global__ __launch_bounds__(256) void ks1b(
    const int* ei, const void* ew, int* cursor, uint2* esrt, int E, int N, int nb) {
  __shared__ int   hist[MAXNB];        // counts -> later destL      4 KB
  __shared__ int   sArr[MAXNB + 1];    // bucket starts in recs      4 KB
  __shared__ int   psum[256];          //                            1 KB
  __shared__ uint2 recs[CHUNK];        //                           16 KB
  __shared__ u16   bof[CHUNK];         // bucket of record           4 KB
  const bool i64 = detect_i64(ei);
  const bool bf  = detect_bf16((const u32*)ew);
  const int tid   = threadIdx.x;
  const int cbase = blockIdx.x * CHUNK;

  for (int i = tid; i < MAXNB; i += 256) hist[i] = 0;
  __syncthreads();

  int bkt[8], rank[8]; u32 px[8], wb[8]; bool val[8];
#pragma unroll
  for (int r = 0; r < 8; ++r) {
    const int e = cbase + r * 256 + tid;
    val[r] = false;
    if (e < E) {
      int dst, src;
      if (i64) { dst = ei[2 * (size_t)e]; src = ei[2 * ((size_t)E + e)]; }
      else     { dst = ei[e];             src = ei[(size_t)E + e]; }
      if ((unsigned)dst < (unsigned)N && (unsigned)src < (unsigned)N) {
        val[r] = true;
        bkt[r] = dst >> BSH;
        px[r]  = (u32)src | ((u32)(dst & ((1 << BSH) - 1)) << 17);
        float w;
        if (bf) w = bf2f(((const u16*)ew)[e]); else w = ((const float*)ew)[e];
        wb[r] = __float_as_uint(w);
        rank[r] = atomicAdd(&hist[bkt[r]], 1);
      }
    }
  }
  __syncthreads();

  // exclusive scan of hist -> sArr (256 threads x 4 bins)
  const int g0 = tid * 4;
  int loc[4], ts = 0;
#pragma unroll
  for (int i = 0; i < 4; ++i) { loc[i] = ts; ts += hist[g0 + i]; }
  psum[tid] = ts; __syncthreads();
#pragma unroll
  for (int off = 1; off < 256; off <<= 1) {
    int t = (tid >= off) ? psum[tid - off] : 0;
    __syncthreads();
    psum[tid] += t;
    __syncthreads();
  }
  const int excl = psum[tid] - ts;
#pragma unroll
  for (int i = 0; i < 4; ++i) sArr[g0 + i] = excl + loc[i];
  if (tid == 255) sArr[MAXNB] = psum[255];
  __syncthreads();

  // scatter into recs (bucket-sorted) + record each record's bucket
#pragma unroll
  for (int r = 0; r < 8; ++r) if (val[r]) {
    const int idx = sArr[bkt[r]] + rank[r];
    recs[idx] = make_uint2(px[r], wb[r]);
    bof[idx]  = (u16)bkt[r];
  }
  __syncthreads();

  // claim one contiguous global run per nonzero (chunk,bucket); hist := dest base
  for (int b = tid; b < nb; b += 256) {
    const int c = sArr[b + 1] - sArr[b];
    if (c > 0) hist[b] = atomicAdd(&cursor[b], c);
  }
  const int vcnt = sArr[nb];
  __syncthreads();

  // write records to final bucket-contiguous positions
  for (int i = tid; i < vcnt; i += 256) {
    const int b = bof[i];
    esrt[hist[b] + (i - sArr[b])] = recs[i];
  }
}

// ====== kagg3: bucket-owned aggregate over CONTIGUOUS edge run + fused finalize ======
// 512 threads (8 waves), 64 KB LDS accumulator -> 2 blocks/CU = 16 waves/CU.
// Inner loop = old kagg's 4-deep gather ILP. ds_add_f32 into split layout:
// feature 2l at [n][l], 2l+1 at [n][64+l] (2-way bank alias = free).
extern "C" __global__ __launch_bounds__(512) void kagg3(
    const uint2* esrt, const int* bbase, const u16* xt,
    void* out, const void* xdet, int N) {
  __shared__ float sup[128 * 128];          // 64 KB
  const bool bf = detect_bf16((const u32*)xdet);
  const int tid = threadIdx.x;
  const int lane = tid & 63, wid = tid >> 6;   // wid 0..7
  const int b = blockIdx.x;
  const int node0 = b << BSH;
  {
    const f32x4 z = {0.f, 0.f, 0.f, 0.f};
    for (int i = tid * 4; i < 128 * 128; i += 2048) *(f32x4*)&sup[i] = z;
  }
  __syncthreads();

  const int s0 = bbase[b], s1 = bbase[b + 1];
  const u32* xtw = (const u32*)xt;
  for (int base = s0 + wid * 64; base < s1; base += 512) {
    const int m = min(64, s1 - base);
    uint2 ed = make_uint2(0u, 0u);
    if (lane < m) ed = esrt[base + lane];    // coalesced 512B edge-chunk load
    int i = 0;
    for (; i + 4 <= m; i += 4) {
      const u32 pA = __shfl(ed.x, i),     pB = __shfl(ed.x, i + 1);
      const u32 pC = __shfl(ed.x, i + 2), pD = __shfl(ed.x, i + 3);
      const u32 uA = xtw[(size_t)(pA & 0x1FFFFu) * 64 + lane];   // 4 gathers in flight
      const u32 uB = xtw[(size_t)(pB & 0x1FFFFu) * 64 + lane];
      const u32 uC = xtw[(size_t)(pC & 0x1FFFFu) * 64 + lane];
      const u32 uD = xtw[(size_t)(pD & 0x1FFFFu) * 64 + lane];
      const float wA = __uint_as_float(__shfl(ed.y, i));
      const float wB = __uint_as_float(__shfl(ed.y, i + 1));
      const float wC = __uint_as_float(__shfl(ed.y, i + 2));
      const float wD = __uint_as_float(__shfl(ed.y, i + 3));
      const int dA = (pA >> 17) & 127, dB = (pB >> 17) & 127;
      const int dC = (pC >> 17) & 127, dD = (pD >> 17) & 127;
      atomicAdd(&sup[dA * 128 + lane],      wA * bflo(uA));
      atomicAdd(&sup[dA * 128 + 64 + lane], wA * bfhi(uA));
      atomicAdd(&sup[dB * 128 + lane],      wB * bflo(uB));
      atomicAdd(&sup[dB * 128 + 64 + lane], wB * bfhi(uB));
      atomicAdd(&sup[dC * 128 + lane],      wC * bflo(uC));
      atomicAdd(&sup[dC * 128 + 64 + lane], wC * bfhi(uC));
      atomicAdd(&sup[dD * 128 + lane],      wD * bflo(uD));
      atomicAdd(&sup[dD * 128 + 64 + lane], wD * bfhi(uD));
    }
    for (; i < m; ++i) {
      const u32 p = __shfl(ed.x, i);
      const float w = __uint_as_float(__shfl(ed.y, i));
      const u32 u = xtw[(size_t)(p & 0x1FFFFu) * 64 + lane];
      const int d = (p >> 17) & 127;
      atomicAdd(&sup[d * 128 + lane],      w * bflo(u));
      atomicAdd(&sup[d * 128 + 64 + lane], w * bfhi(u));
    }
  }
  __syncthreads();

  // finalize: expmap0 -> proj -> logmap0 -> relu -> expmap0 -> proj
  for (int n = wid; n < 128; n += 8) {
    const int node = node0 + n;
    if (node >= N) continue;
    const float a0 = sup[n * 128 + lane];        // feature 2*lane
    const float a1 = sup[n * 128 + 64 + lane];   // feature 2*lane+1
    float nn0 = fmaxf(sqrtf(wsum(a0 * a0 + a1 * a1)), MINNORM);
    float tn = fast_tanh(nn0);
    float mm = tn * frcp(nn0);
    if (tn > MAXNORM) { mm *= MAXNORM * frcp(tn); tn = MAXNORM; }
    float nn = fmaxf(tn, MINNORM);
    mm *= fast_artanh(nn) * frcp(nn);
    float tA = fmaxf(mm * a0, 0.f), tB = fmaxf(mm * a1, 0.f);
    float nr = fmaxf(sqrtf(wsum(tA * tA + tB * tB)), MINNORM);
    float t2 = fast_tanh(nr);
    float m2 = t2 * frcp(nr);
    if (t2 > MAXNORM) m2 *= MAXNORM * frcp(t2);
    float oA = m2 * tA, oB = m2 * tB;
    if (bf) {
      u32 o = ((u32)f2bf(oA)) | (((u32)f2bf(oB)) << 16);
      ((u32*)out)[(size_t)node * 64 + lane] = o;
    } else {
      ((float2*)out)[(size_t)node * 64 + lane] = make_float2(oA, oB);
    }
  }
}

extern "C" void kernel_launch(void* const* d_in, const int* in_sizes, int n_in,
                              void* d_out, int out_size, void* d_ws, size_t ws_size,
                              hipStream_t stream) {
  const void* x    = d_in[0];
  const void* W    = d_in[1];
  const void* bias = d_in[2];
  const int*  ei   = (const int*)d_in[3];
  const void* ew   = d_in[4];
  const int N = in_sizes[0] / D;
  const int E = in_sizes[4];
  const int nchunks = (E + CHUNK - 1) / CHUNK;
  const int nb      = (N + (1 << BSH) - 1) >> BSH;

  char* ws = (char*)d_ws;
  size_t off = 0;
  auto carve = [&](size_t bytes) { char* p = ws + off; off = (off + bytes + 255) & ~(size_t)255; return p; };
  u16*   xt     = (u16*)  carve((size_t)N * D * sizeof(u16));         // 25.6 MB
  uint2* esrt   = (uint2*)carve((size_t)E * sizeof(uint2));           // 12.8 MB
  u16*   cnt    = (u16*)  carve((size_t)nchunks * nb * sizeof(u16));  // 1.2 MB
  int*   btot   = (int*)  carve((size_t)nb * sizeof(int));
  int*   bbase  = (int*)  carve((size_t)(nb + 1) * sizeof(int));
  int*   cursor = (int*)  carve((size_t)nb * sizeof(int));

  OriginHyperbolicGraphConvolution_38628935860614_kernel<<<(N + 63) / 64, 256, 0, stream>>>(
      x, W, bias, xt, N);
  ks1a  <<<nchunks, 256, 0, stream>>>(ei, cnt, E, N, nb);
  ks2sum<<<nb, 256, 0, stream>>>(cnt, btot, nb, nchunks);
  ks2scan<<<1, 1024, 0, stream>>>(btot, bbase, cursor, nb);
  ks1b  <<<nchunks, 256, 0, stream>>>(ei, ew, cursor, esrt, E, N, nb);
  kagg3 <<<nb, 512, 0, stream>>>(esrt, bbase, xt, d_out, x, N);
}

// Round 4
// 280.532 us; speedup vs baseline: 5.8946x; 5.6638x over previous
//
#include <hip/hip_runtime.h>
#include <math.h>

#define D 128
#define MAXNORM 0.996f            // (1 - 4e-3)/sqrt(c), c = 1
#define MINNORM 1e-15f
#define ATCLAMP (1.0f - 1e-7f)

#define CHUNK 2048                // edges per sort block (8 per thread)
#define BSH   7                   // 128 nodes per bucket
#define MAXNB 1024                // supports N <= 131072 (problem: N = 100000)

typedef unsigned int   u32;
typedef unsigned short u16;

typedef __attribute__((ext_vector_type(8))) short bf16x8;
typedef __attribute__((ext_vector_type(4))) float f32x4;

__device__ __forceinline__ float wsum(float v) {
#pragma unroll
  for (int m = 32; m; m >>= 1) v += __shfl_xor(v, m);
  return v;
}
// 16-lane reduction (stays within a lane&48 group) — matches MFMA C-layout rows
__device__ __forceinline__ float rsum16(float v) {
#pragma unroll
  for (int m = 1; m <= 8; m <<= 1) v += __shfl_xor(v, m);
  return v;
}

__device__ __forceinline__ float frcp(float x) { return __builtin_amdgcn_rcpf(x); }

// fast artanh for x in [0, 1-1e-7]
__device__ __forceinline__ float fast_artanh(float x) {
  x = fminf(x, ATCLAMP);
  return 0.5f * __logf((1.0f + x) * frcp(1.0f - x));
}
// fast tanh for z >= 0
__device__ __forceinline__ float fast_tanh(float z) {
  float t = __expf(-2.0f * z);
  return (1.0f - t) * frcp(1.0f + t);
}

__device__ __forceinline__ float bflo(u32 u) { return __uint_as_float(u << 16); }
__device__ __forceinline__ float bfhi(u32 u) { return __uint_as_float(u & 0xffff0000u); }
__device__ __forceinline__ u16 f2bf(float f) {            // RNE f32 -> bf16
  u32 u = __float_as_uint(f);
  return (u16)((u + 0x7fffu + ((u >> 16) & 1u)) >> 16);
}
__device__ __forceinline__ float bf2f(u16 h) { return __uint_as_float(((u32)h) << 16); }

union U4B8 { uint4 u; bf16x8 b; };
__device__ __forceinline__ bf16x8 as_b8(uint4 v) { U4B8 c; c.u = v; return c.b; }

// ---- runtime dtype detection (wave-uniform; call before any divergence) ----
__device__ __forceinline__ bool detect_bf16(const u32* p) {
  float lo = fabsf(bflo(p[threadIdx.x & 63]));
  return (bool)__all(lo < 1.0f);
}
__device__ __forceinline__ bool detect_i64(const int* p) {
  return (bool)__all(p[2 * (threadIdx.x & 63) + 1] == 0);
}

// ====== K1: MFMA mobius_matvec + proj + mobius_add(bias) + proj + logmap0 ======
// (verified rounds 1-3) One 16x128 output tile per wave via mfma_f32_16x16x32_bf16;
// W staged in LDS in B-fragment order; fp32 path uses bf16x3 split.
// C layout (m89-verified): col = lane&15, row = (lane>>4)*4 + reg.
template<bool BF>
__device__ __forceinline__ void k1_body(const void* xv, const void* Wv,
                                        const void* bv, u16* xt, int N,
                                        uint4* Wh, uint4* Wl) {
  const int tid  = threadIdx.x;
  const int lane = tid & 63;
  const int wid  = tid >> 6;
  const int qg   = lane >> 4;   // k-block group 0..3
  const int lc   = lane & 15;   // col within 16-wide tile

  for (int slot = tid; slot < 2048; slot += 256) {
    const int l = slot & 63, frag = slot >> 6;
    const int t = frag >> 2, ks = frag & 3;
    const int j  = (l & 15) + 16 * t;
    const int k0 = 32 * ks + 8 * (l >> 4);
    if (BF) {
      Wh[slot] = ((const uint4*)Wv)[j * 16 + (k0 >> 3)];
    } else {
      const float* Wf = (const float*)Wv;
      float4 f0 = *(const float4*)(Wf + (size_t)j * D + k0);
      float4 f1 = *(const float4*)(Wf + (size_t)j * D + k0 + 4);
      float f[8] = {f0.x, f0.y, f0.z, f0.w, f1.x, f1.y, f1.z, f1.w};
      u32 hw[4], lw[4];
#pragma unroll
      for (int i = 0; i < 4; ++i) {
        u16 h0 = f2bf(f[2*i]),  h1 = f2bf(f[2*i+1]);
        u16 l0 = f2bf(f[2*i]   - bf2f(h0));
        u16 l1 = f2bf(f[2*i+1] - bf2f(h1));
        hw[i] = (u32)h0 | ((u32)h1 << 16);
        lw[i] = (u32)l0 | ((u32)l1 << 16);
      }
      Wh[slot] = make_uint4(hw[0], hw[1], hw[2], hw[3]);
      Wl[slot] = make_uint4(lw[0], lw[1], lw[2], lw[3]);
    }
  }

  float bfr[8];
  float nb2 = 0.f;
#pragma unroll
  for (int t = 0; t < 8; ++t) {
    float v = BF ? bf2f(((const u16*)bv)[lc + 16 * t])
                 : ((const float*)bv)[lc + 16 * t];
    bfr[t] = v; nb2 += v * v;
  }
  nb2 = rsum16(nb2);
  float y2;
  {
    float nb = fmaxf(sqrtf(nb2), MINNORM);
    float s  = fast_tanh(nb) * frcp(nb);
    float n1 = s * nb;
    if (n1 > MAXNORM) s *= MAXNORM * frcp(n1);
#pragma unroll
    for (int t = 0; t < 8; ++t) bfr[t] *= s;
    y2 = s * s * nb2;
  }
  const bool bias_zero = (y2 == 0.0f);

  __syncthreads();

  const int tile  = blockIdx.x * 4 + wid;
  const int rbase = tile * 16;
  if (rbase >= N) return;

  int rowA = rbase + lc; if (rowA >= N) rowA = N - 1;
  uint4 Ah[4], Al[4];
  float xn2 = 0.f;
  if (BF) {
    const uint4* xr = (const uint4*)((const u16*)xv + (size_t)rowA * D);
#pragma unroll
    for (int ks = 0; ks < 4; ++ks) {
      uint4 v = xr[4 * ks + qg];
      Ah[ks] = v;
      float a0 = bflo(v.x), a1 = bfhi(v.x), a2 = bflo(v.y), a3 = bfhi(v.y);
      float a4 = bflo(v.z), a5 = bfhi(v.z), a6 = bflo(v.w), a7 = bfhi(v.w);
      xn2 += a0*a0 + a1*a1 + a2*a2 + a3*a3 + a4*a4 + a5*a5 + a6*a6 + a7*a7;
    }
  } else {
    const float4* xr = (const float4*)((const float*)xv + (size_t)rowA * D);
#pragma unroll
    for (int ks = 0; ks < 4; ++ks) {
      float4 f0 = xr[8 * ks + 2 * qg], f1 = xr[8 * ks + 2 * qg + 1];
      float f[8] = {f0.x, f0.y, f0.z, f0.w, f1.x, f1.y, f1.z, f1.w};
      u32 hw[4], lw[4];
#pragma unroll
      for (int i = 0; i < 4; ++i) {
        u16 h0 = f2bf(f[2*i]),  h1 = f2bf(f[2*i+1]);
        u16 l0 = f2bf(f[2*i]   - bf2f(h0));
        u16 l1 = f2bf(f[2*i+1] - bf2f(h1));
        hw[i] = (u32)h0 | ((u32)h1 << 16);
        lw[i] = (u32)l0 | ((u32)l1 << 16);
        xn2 += f[2*i] * f[2*i] + f[2*i+1] * f[2*i+1];
      }
      Ah[ks] = make_uint4(hw[0], hw[1], hw[2], hw[3]);
      Al[ks] = make_uint4(lw[0], lw[1], lw[2], lw[3]);
    }
  }
  xn2 += __shfl_xor(xn2, 16);
  xn2 += __shfl_xor(xn2, 32);

  f32x4 acc[8];
  const f32x4 zero = {0.f, 0.f, 0.f, 0.f};
#pragma unroll
  for (int t = 0; t < 8; ++t) acc[t] = zero;
#pragma unroll
  for (int ks = 0; ks < 4; ++ks) {
    bf16x8 a = as_b8(Ah[ks]);
    bf16x8 al;
    if (!BF) al = as_b8(Al[ks]);
#pragma unroll
    for (int t = 0; t < 8; ++t) {
      const int idx = (t * 4 + ks) * 64 + lane;
      bf16x8 bh = as_b8(Wh[idx]);
      acc[t] = __builtin_amdgcn_mfma_f32_16x16x32_bf16(a, bh, acc[t], 0, 0, 0);
      if (!BF) {
        bf16x8 bl = as_b8(Wl[idx]);
        acc[t] = __builtin_amdgcn_mfma_f32_16x16x32_bf16(al, bh, acc[t], 0, 0, 0);
        acc[t] = __builtin_amdgcn_mfma_f32_16x16x32_bf16(a,  bl, acc[t], 0, 0, 0);
      }
    }
  }

#pragma unroll
  for (int q = 0; q < 4; ++q) {
    const int row_off = qg * 4 + q;
    const int row = rbase + row_off;
    float xnq = fmaxf(sqrtf(__shfl(xn2, row_off)), MINNORM);
    float s2 = 0.f;
#pragma unroll
    for (int t = 0; t < 8; ++t) { float v = acc[t][q]; s2 += v * v; }
    s2 = rsum16(s2);
    float mxn = fmaxf(sqrtf(s2), MINNORM);
    float r = fast_tanh(mxn * frcp(xnq) * fast_artanh(xnq)) * frcp(mxn);
    float pn = r * mxn;
    if (pn > MAXNORM) { r *= MAXNORM * frcp(pn); pn = MAXNORM; }
    float h[8];
    float hn;
    if (bias_zero) {
#pragma unroll
      for (int t = 0; t < 8; ++t) h[t] = r * acc[t][q];
      hn = pn;
    } else {
      float xy = 0.f;
#pragma unroll
      for (int t = 0; t < 8; ++t) { h[t] = r * acc[t][q]; xy += h[t] * bfr[t]; }
      xy = rsum16(xy);
      float x2 = pn * pn;
      float ca = 1.f + 2.f * xy + y2;
      float cb = 1.f - x2;
      float id = frcp(fmaxf(1.f + 2.f * xy + x2 * y2, MINNORM));
      float s3 = 0.f;
#pragma unroll
      for (int t = 0; t < 8; ++t) { h[t] = (ca * h[t] + cb * bfr[t]) * id; s3 += h[t] * h[t]; }
      hn = fmaxf(sqrtf(rsum16(s3)), MINNORM);
    }
    float ps = (hn > MAXNORM) ? (MAXNORM * frcp(hn)) : 1.f;
    float np = fmaxf(hn * ps, MINNORM);
    float tsc = fast_artanh(np) * frcp(np) * ps;
    if (row < N) {
      u16* xo = xt + (size_t)row * D + lc;
#pragma unroll
      for (int t = 0; t < 8; ++t) xo[16 * t] = f2bf(tsc * h[t]);
    }
  }
}

extern "C" __global__ __launch_bounds__(256)
void OriginHyperbolicGraphConvolution_38628935860614_kernel(
    const void* x, const void* W, const void* b, u16* xt, int N) {
  __shared__ uint4 Wh[2048];   // 32 KB
  __shared__ uint4 Wl[2048];   // 32 KB (fp32 input path only)
  if (detect_bf16((const u32*)x)) k1_body<true >(x, W, b, xt, N, Wh, Wl);
  else                            k1_body<false>(x, W, b, xt, N, Wh, Wl);
}

// ====== ks1a: per-chunk bucket histogram -> u16 count row (coalesced) ======
extern "C" __global__ __launch_bounds__(256) void ks1a(
    const int* ei, u16* cnt, int E, int N, int nb) {
  __shared__ int hist[MAXNB];     // 4 KB
  const bool i64 = detect_i64(ei);
  const int tid = threadIdx.x;
  const int cbase = blockIdx.x * CHUNK;
  for (int i = tid; i < MAXNB; i += 256) hist[i] = 0;
  __syncthreads();
#pragma unroll
  for (int r = 0; r < 8; ++r) {
    const int e = cbase + r * 256 + tid;
    if (e < E) {
      int dst, src;
      if (i64) { dst = ei[2 * (size_t)e]; src = ei[2 * ((size_t)E + e)]; }
      else     { dst = ei[e];             src = ei[(size_t)E + e]; }
      if ((unsigned)dst < (unsigned)N && (unsigned)src < (unsigned)N)
        atomicAdd(&hist[dst >> BSH], 1);
    }
  }
  __syncthreads();
  u16* row = cnt + (size_t)blockIdx.x * nb;
  for (int b = tid; b < nb; b += 256) row[b] = (u16)hist[b];
}

// ====== ks2sum: per-bucket total = column sum over chunks (cnt is L2-resident) ======
extern "C" __global__ __launch_bounds__(256) void ks2sum(
    const u16* cnt, int* btot, int nb, int nchunks) {
  __shared__ int red[256];
  const int b = blockIdx.x, tid = threadIdx.x;
  int s = 0;
  for (int c = tid; c < nchunks; c += 256) s += cnt[(size_t)c * nb + b];
  red[tid] = s; __syncthreads();
#pragma unroll
  for (int off = 128; off; off >>= 1) {
    if (tid < off) red[tid] += red[tid + off];
    __syncthreads();
  }
  if (tid == 0) btot[b] = red[0];
}

// ====== ks2scan: bucket bases + cursor init (nb <= 1024) ======
extern "C" __global__ __launch_bounds__(1024) void ks2scan(
    const int* btot, int* bbase, int* cursor, int nb) {
  __shared__ int sc[1024];
  const int t = threadIdx.x;
  int v = (t < nb) ? btot[t] : 0;
  sc[t] = v; __syncthreads();
#pragma unroll
  for (int off = 1; off < 1024; off <<= 1) {
    int u = (t >= off) ? sc[t - off] : 0;
    __syncthreads();
    sc[t] += u;
    __syncthreads();
  }
  if (t < nb) { int o = sc[t] - v; bbase[t] = o; cursor[t] = o; }
  if (t == 1023) bbase[nb] = sc[1023];
}

// ====== ks1b: chunk-local counting sort + run-claim scatter to bucket-contiguous ebuck ======
// Per (chunk,bucket) run of ~2.6 records: ONE global atomicAdd claims a contiguous
// destination run; records written piecewise-contiguous (~3x line amp, not 8x).
extern "C" __global__ __launch_bounds__(256) void ks1b(
    const int* ei, const void* ew, int* cursor, uint2* ebuck, int E, int N, int nb) {
  __shared__ int   hist[MAXNB];        // counts -> later dest base  4 KB
  __shared__ int   sArr[MAXNB + 1];    // bucket starts in recs      4 KB
  __shared__ int   psum[256];          //                            1 KB
  __shared__ uint2 recs[CHUNK];        //                           16 KB
  __shared__ u16   bof[CHUNK];         // bucket of record           4 KB
  const bool i64 = detect_i64(ei);
  const bool bf  = detect_bf16((const u32*)ew);
  const int tid   = threadIdx.x;
  const int cbase = blockIdx.x * CHUNK;

  for (int i = tid; i < MAXNB; i += 256) hist[i] = 0;
  __syncthreads();

  int bkt[8], rank[8]; u32 px[8], wb[8]; bool val[8];
#pragma unroll
  for (int r = 0; r < 8; ++r) {
    const int e = cbase + r * 256 + tid;
    val[r] = false;
    if (e < E) {
      int dst, src;
      if (i64) { dst = ei[2 * (size_t)e]; src = ei[2 * ((size_t)E + e)]; }
      else     { dst = ei[e];             src = ei[(size_t)E + e]; }
      if ((unsigned)dst < (unsigned)N && (unsigned)src < (unsigned)N) {
        val[r] = true;
        bkt[r] = dst >> BSH;
        px[r]  = (u32)src | ((u32)(dst & ((1 << BSH) - 1)) << 17);
        float w;
        if (bf) w = bf2f(((const u16*)ew)[e]); else w = ((const float*)ew)[e];
        wb[r] = __float_as_uint(w);
        rank[r] = atomicAdd(&hist[bkt[r]], 1);
      }
    }
  }
  __syncthreads();

  // exclusive scan of hist -> sArr (256 threads x 4 bins)
  const int g0 = tid * 4;
  int loc[4], ts = 0;
#pragma unroll
  for (int i = 0; i < 4; ++i) { loc[i] = ts; ts += hist[g0 + i]; }
  psum[tid] = ts; __syncthreads();
#pragma unroll
  for (int off = 1; off < 256; off <<= 1) {
    int t = (tid >= off) ? psum[tid - off] : 0;
    __syncthreads();
    psum[tid] += t;
    __syncthreads();
  }
  const int excl = psum[tid] - ts;
#pragma unroll
  for (int i = 0; i < 4; ++i) sArr[g0 + i] = excl + loc[i];
  if (tid == 255) sArr[MAXNB] = psum[255];
  __syncthreads();

  // scatter into recs (bucket-sorted) + record each record's bucket
#pragma unroll
  for (int r = 0; r < 8; ++r) if (val[r]) {
    const int idx = sArr[bkt[r]] + rank[r];
    recs[idx] = make_uint2(px[r], wb[r]);
    bof[idx]  = (u16)bkt[r];
  }
  __syncthreads();

  // claim one contiguous global run per nonzero (chunk,bucket); hist := dest base
  for (int b = tid; b < nb; b += 256) {
    const int c = sArr[b + 1] - sArr[b];
    if (c > 0) hist[b] = atomicAdd(&cursor[b], c);
  }
  const int vcnt = sArr[nb];
  __syncthreads();

  // write records to final bucket-contiguous positions
  for (int i = tid; i < vcnt; i += 256) {
    const int b = bof[i];
    ebuck[hist[b] + (i - sArr[b])] = recs[i];
  }
}

// ====== ks3: finish sort within bucket + emit per-node offsets ======
// Block per bucket (~2046 records, ~16 KB segment). Per-node LDS histogram ->
// scan -> per-record scatter. Scatter window is single-block-owned and
// L2-resident (16 KB), so write amplification ~1 (unlike the old cross-XCD
// 12.8 MB scatter). Also writes offs[node] = bbase[b] + in-bucket start, and
// offs[N] from the last bucket — replaces khist + 3 scan kernels.
extern "C" __global__ __launch_bounds__(256) void ks3(
    const uint2* ebuck, const int* bbase, uint2* esrt, int* offs, int N, int nb) {
  __shared__ int hist[128];
  __shared__ int sc[128];
  __shared__ int cur[128];
  const int tid = threadIdx.x;
  const int b = blockIdx.x;
  const int s0 = bbase[b], s1 = bbase[b + 1];
  const int node0 = b << BSH;
  if (tid < 128) hist[tid] = 0;
  __syncthreads();
  for (int i = s0 + tid; i < s1; i += 256)
    atomicAdd(&hist[(ebuck[i].x >> 17) & 127], 1);
  __syncthreads();
  int v = 0;
  if (tid < 128) { v = hist[tid]; sc[tid] = v; }
  __syncthreads();
#pragma unroll
  for (int off = 1; off < 128; off <<= 1) {
    int t = (tid < 128 && tid >= off) ? sc[tid - off] : 0;
    __syncthreads();
    if (tid < 128) sc[tid] += t;
    __syncthreads();
  }
  if (tid < 128) {
    const int st = sc[tid] - v;        // exclusive in-bucket start
    cur[tid] = st;
    const int node = node0 + tid;
    if (node < N) offs[node] = s0 + st;
  }
  if (tid == 0 && b == nb - 1) offs[N] = s1;
  __syncthreads();
  for (int i = s0 + tid; i < s1; i += 256) {
    const uint2 r = ebuck[i];
    const int d = atomicAdd(&cur[(r.x >> 17) & 127], 1);
    esrt[s0 + d] = make_uint2(r.x & 0x1FFFFu, r.y);   // plain src + w bits
  }
}

// ====== kagg: gather-aggregate per node + fused finalize (round-1 verified) ======
// Wave per node, REGISTER accumulation. Edge list loaded cooperatively (one
// coalesced vector load per <=64-edge chunk), broadcast via shfl, 4 gathers deep.
extern "C" __global__ __launch_bounds__(256) void kagg(
    const int* offs, const uint2* esrt, const u16* xt,
    void* out, const void* xdet, int N) {
  const bool bf = detect_bf16((const u32*)xdet);
  const int lane = threadIdx.x & 63;
  const int node = blockIdx.x * 4 + (threadIdx.x >> 6);
  if (node >= N) return;
  const int s0 = offs[node], s1 = offs[node + 1];
  const u32* xtw = (const u32*)xt;
  float a0 = 0.f, a1 = 0.f;
  for (int base = s0; base < s1; base += 64) {
    const int m = min(64, s1 - base);
    uint2 ed = make_uint2(0u, 0u);
    if (lane < m) ed = esrt[base + lane];    // coalesced 512B edge-chunk load
    int i = 0;
    for (; i + 4 <= m; i += 4) {
      const u32 sA = __shfl(ed.x, i),     sB = __shfl(ed.x, i + 1);
      const u32 sC = __shfl(ed.x, i + 2), sD = __shfl(ed.x, i + 3);
      const u32 uA = xtw[(size_t)sA * 64 + lane];   // 4 gathers in flight
      const u32 uB = xtw[(size_t)sB * 64 + lane];
      const u32 uC = xtw[(size_t)sC * 64 + lane];
      const u32 uD = xtw[(size_t)sD * 64 + lane];
      const float wA = __uint_as_float(__shfl(ed.y, i));
      const float wB = __uint_as_float(__shfl(ed.y, i + 1));
      const float wC = __uint_as_float(__shfl(ed.y, i + 2));
      const float wD = __uint_as_float(__shfl(ed.y, i + 3));
      a0 += wA * bflo(uA) + wB * bflo(uB) + wC * bflo(uC) + wD * bflo(uD);
      a1 += wA * bfhi(uA) + wB * bfhi(uB) + wC * bfhi(uC) + wD * bfhi(uD);
    }
    for (; i < m; ++i) {
      const u32 s = __shfl(ed.x, i);
      const float w = __uint_as_float(__shfl(ed.y, i));
      const u32 u = xtw[(size_t)s * 64 + lane];
      a0 += w * bflo(u);
      a1 += w * bfhi(u);
    }
  }
  // finalize: expmap0 -> proj -> logmap0 -> relu -> expmap0 -> proj
  float n = fmaxf(sqrtf(wsum(a0 * a0 + a1 * a1)), MINNORM);
  float tn = fast_tanh(n);
  float m = tn * frcp(n);
  if (tn > MAXNORM) { m *= MAXNORM * frcp(tn); tn = MAXNORM; }
  float nn = fmaxf(tn, MINNORM);
  m *= fast_artanh(nn) * frcp(nn);
  float tA = fmaxf(m * a0, 0.f), tB = fmaxf(m * a1, 0.f);
  float nr = fmaxf(sqrtf(wsum(tA * tA + tB * tB)), MINNORM);
  float t2 = fast_tanh(nr);
  float m2 = t2 * frcp(nr);
  if (t2 > MAXNORM) m2 *= MAXNORM * frcp(t2);
  float oA = m2 * tA, oB = m2 * tB;
  if (bf) {
    u32 o = ((u32)f2bf(oA)) | (((u32)f2bf(oB)) << 16);
    ((u32*)out)[(size_t)node * 64 + lane] = o;
  } else {
    ((float2*)out)[(size_t)node * 64 + lane] = make_float2(oA, oB);
  }
}

extern "C" void kernel_launch(void* const* d_in, const int* in_sizes, int n_in,
                              void* d_out, int out_size, void* d_ws, size_t ws_size,
                              hipStream_t stream) {
  const void* x    = d_in[0];
  const void* W    = d_in[1];
  const void* bias = d_in[2];
  const int*  ei   = (const int*)d_in[3];
  const void* ew   = d_in[4];
  const int N = in_sizes[0] / D;
  const int E = in_sizes[4];
  const int nchunks = (E + CHUNK - 1) / CHUNK;
  const int nb      = (N + (1 << BSH) - 1) >> BSH;

  char* ws = (char*)d_ws;
  size_t off = 0;
  auto carve = [&](size_t bytes) { char* p = ws + off; off = (off + bytes + 255) & ~(size_t)255; return p; };
  u16*   xt     = (u16*)  carve((size_t)N * D * sizeof(u16));         // 25.6 MB
  uint2* ebuck  = (uint2*)carve((size_t)E * sizeof(uint2));           // 12.8 MB
  uint2* esrt   = (uint2*)carve((size_t)E * sizeof(uint2));           // 12.8 MB
  u16*   cnt    = (u16*)  carve((size_t)nchunks * nb * sizeof(u16));  // 1.2 MB
  int*   btot   = (int*)  carve((size_t)nb * sizeof(int));
  int*   bbase  = (int*)  carve((size_t)(nb + 1) * sizeof(int));
  int*   cursor = (int*)  carve((size_t)nb * sizeof(int));
  int*   offs   = (int*)  carve((size_t)(N + 1) * sizeof(int));       // 0.4 MB

  OriginHyperbolicGraphConvolution_38628935860614_kernel<<<(N + 63) / 64, 256, 0, stream>>>(
      x, W, bias, xt, N);
  ks1a  <<<nchunks, 256, 0, stream>>>(ei, cnt, E, N, nb);
  ks2sum<<<nb, 256, 0, stream>>>(cnt, btot, nb, nchunks);
  ks2scan<<<1, 1024, 0, stream>>>(btot, bbase, cursor, nb);
  ks1b  <<<nchunks, 256, 0, stream>>>(ei, ew, cursor, ebuck, E, N, nb);
  ks3   <<<nb, 256, 0, stream>>>(ebuck, bbase, esrt, offs, N, nb);
  kagg  <<<(N + 3) / 4, 256, 0, stream>>>(offs, esrt, xt, d_out, x, N);
}

// Round 5
// 271.397 us; speedup vs baseline: 6.0930x; 1.0337x over previous
//
#include <hip/hip_runtime.h>
#include <math.h>

#define D 128
#define MAXNORM 0.996f            // (1 - 4e-3)/sqrt(c), c = 1
#define MINNORM 1e-15f
#define ATCLAMP (1.0f - 1e-7f)

#define CHUNK 2048                // edges per sort block (8 per thread)
#define BSH   7                   // 128 nodes per bucket
#define MAXNB 1024                // supports N <= 131072 (problem: N = 100000)
#define SCAP  6144                // ks3 LDS staging records (mean ~2046/bucket)

typedef unsigned int   u32;
typedef unsigned short u16;

typedef __attribute__((ext_vector_type(8))) short bf16x8;
typedef __attribute__((ext_vector_type(4))) float f32x4;

__device__ __forceinline__ float wsum(float v) {
#pragma unroll
  for (int m = 32; m; m >>= 1) v += __shfl_xor(v, m);
  return v;
}
// 16-lane reduction (stays within a lane&48 group) — matches MFMA C-layout rows
__device__ __forceinline__ float rsum16(float v) {
#pragma unroll
  for (int m = 1; m <= 8; m <<= 1) v += __shfl_xor(v, m);
  return v;
}

__device__ __forceinline__ float frcp(float x) { return __builtin_amdgcn_rcpf(x); }

// fast artanh for x in [0, 1-1e-7]
__device__ __forceinline__ float fast_artanh(float x) {
  x = fminf(x, ATCLAMP);
  return 0.5f * __logf((1.0f + x) * frcp(1.0f - x));
}
// fast tanh for z >= 0
__device__ __forceinline__ float fast_tanh(float z) {
  float t = __expf(-2.0f * z);
  return (1.0f - t) * frcp(1.0f + t);
}

__device__ __forceinline__ float bflo(u32 u) { return __uint_as_float(u << 16); }
__device__ __forceinline__ float bfhi(u32 u) { return __uint_as_float(u & 0xffff0000u); }
__device__ __forceinline__ u16 f2bf(float f) {            // RNE f32 -> bf16
  u32 u = __float_as_uint(f);
  return (u16)((u + 0x7fffu + ((u >> 16) & 1u)) >> 16);
}
__device__ __forceinline__ float bf2f(u16 h) { return __uint_as_float(((u32)h) << 16); }

union U4B8 { uint4 u; bf16x8 b; };
__device__ __forceinline__ bf16x8 as_b8(uint4 v) { U4B8 c; c.u = v; return c.b; }

// ---- runtime dtype detection (wave-uniform; call before any divergence) ----
__device__ __forceinline__ bool detect_bf16(const u32* p) {
  float lo = fabsf(bflo(p[threadIdx.x & 63]));
  return (bool)__all(lo < 1.0f);
}
__device__ __forceinline__ bool detect_i64(const int* p) {
  return (bool)__all(p[2 * (threadIdx.x & 63) + 1] == 0);
}

// ====== K1: MFMA mobius_matvec + proj + mobius_add(bias) + proj + logmap0 ======
// (verified rounds 1-4) One 16x128 output tile per wave via mfma_f32_16x16x32_bf16;
// W staged in LDS in B-fragment order; fp32 path uses bf16x3 split.
// C layout (m89-verified): col = lane&15, row = (lane>>4)*4 + reg.
template<bool BF>
__device__ __forceinline__ void k1_body(const void* xv, const void* Wv,
                                        const void* bv, u16* xt, int N,
                                        uint4* Wh, uint4* Wl) {
  const int tid  = threadIdx.x;
  const int lane = tid & 63;
  const int wid  = tid >> 6;
  const int qg   = lane >> 4;   // k-block group 0..3
  const int lc   = lane & 15;   // col within 16-wide tile

  for (int slot = tid; slot < 2048; slot += 256) {
    const int l = slot & 63, frag = slot >> 6;
    const int t = frag >> 2, ks = frag & 3;
    const int j  = (l & 15) + 16 * t;
    const int k0 = 32 * ks + 8 * (l >> 4);
    if (BF) {
      Wh[slot] = ((const uint4*)Wv)[j * 16 + (k0 >> 3)];
    } else {
      const float* Wf = (const float*)Wv;
      float4 f0 = *(const float4*)(Wf + (size_t)j * D + k0);
      float4 f1 = *(const float4*)(Wf + (size_t)j * D + k0 + 4);
      float f[8] = {f0.x, f0.y, f0.z, f0.w, f1.x, f1.y, f1.z, f1.w};
      u32 hw[4], lw[4];
#pragma unroll
      for (int i = 0; i < 4; ++i) {
        u16 h0 = f2bf(f[2*i]),  h1 = f2bf(f[2*i+1]);
        u16 l0 = f2bf(f[2*i]   - bf2f(h0));
        u16 l1 = f2bf(f[2*i+1] - bf2f(h1));
        hw[i] = (u32)h0 | ((u32)h1 << 16);
        lw[i] = (u32)l0 | ((u32)l1 << 16);
      }
      Wh[slot] = make_uint4(hw[0], hw[1], hw[2], hw[3]);
      Wl[slot] = make_uint4(lw[0], lw[1], lw[2], lw[3]);
    }
  }

  float bfr[8];
  float nb2 = 0.f;
#pragma unroll
  for (int t = 0; t < 8; ++t) {
    float v = BF ? bf2f(((const u16*)bv)[lc + 16 * t])
                 : ((const float*)bv)[lc + 16 * t];
    bfr[t] = v; nb2 += v * v;
  }
  nb2 = rsum16(nb2);
  float y2;
  {
    float nb = fmaxf(sqrtf(nb2), MINNORM);
    float s  = fast_tanh(nb) * frcp(nb);
    float n1 = s * nb;
    if (n1 > MAXNORM) s *= MAXNORM * frcp(n1);
#pragma unroll
    for (int t = 0; t < 8; ++t) bfr[t] *= s;
    y2 = s * s * nb2;
  }
  const bool bias_zero = (y2 == 0.0f);

  __syncthreads();

  const int tile  = blockIdx.x * 4 + wid;
  const int rbase = tile * 16;
  if (rbase >= N) return;

  int rowA = rbase + lc; if (rowA >= N) rowA = N - 1;
  uint4 Ah[4], Al[4];
  float xn2 = 0.f;
  if (BF) {
    const uint4* xr = (const uint4*)((const u16*)xv + (size_t)rowA * D);
#pragma unroll
    for (int ks = 0; ks < 4; ++ks) {
      uint4 v = xr[4 * ks + qg];
      Ah[ks] = v;
      float a0 = bflo(v.x), a1 = bfhi(v.x), a2 = bflo(v.y), a3 = bfhi(v.y);
      float a4 = bflo(v.z), a5 = bfhi(v.z), a6 = bflo(v.w), a7 = bfhi(v.w);
      xn2 += a0*a0 + a1*a1 + a2*a2 + a3*a3 + a4*a4 + a5*a5 + a6*a6 + a7*a7;
    }
  } else {
    const float4* xr = (const float4*)((const float*)xv + (size_t)rowA * D);
#pragma unroll
    for (int ks = 0; ks < 4; ++ks) {
      float4 f0 = xr[8 * ks + 2 * qg], f1 = xr[8 * ks + 2 * qg + 1];
      float f[8] = {f0.x, f0.y, f0.z, f0.w, f1.x, f1.y, f1.z, f1.w};
      u32 hw[4], lw[4];
#pragma unroll
      for (int i = 0; i < 4; ++i) {
        u16 h0 = f2bf(f[2*i]),  h1 = f2bf(f[2*i+1]);
        u16 l0 = f2bf(f[2*i]   - bf2f(h0));
        u16 l1 = f2bf(f[2*i+1] - bf2f(h1));
        hw[i] = (u32)h0 | ((u32)h1 << 16);
        lw[i] = (u32)l0 | ((u32)l1 << 16);
        xn2 += f[2*i] * f[2*i] + f[2*i+1] * f[2*i+1];
      }
      Ah[ks] = make_uint4(hw[0], hw[1], hw[2], hw[3]);
      Al[ks] = make_uint4(lw[0], lw[1], lw[2], lw[3]);
    }
  }
  xn2 += __shfl_xor(xn2, 16);
  xn2 += __shfl_xor(xn2, 32);

  f32x4 acc[8];
  const f32x4 zero = {0.f, 0.f, 0.f, 0.f};
#pragma unroll
  for (int t = 0; t < 8; ++t) acc[t] = zero;
#pragma unroll
  for (int ks = 0; ks < 4; ++ks) {
    bf16x8 a = as_b8(Ah[ks]);
    bf16x8 al;
    if (!BF) al = as_b8(Al[ks]);
#pragma unroll
    for (int t = 0; t < 8; ++t) {
      const int idx = (t * 4 + ks) * 64 + lane;
      bf16x8 bh = as_b8(Wh[idx]);
      acc[t] = __builtin_amdgcn_mfma_f32_16x16x32_bf16(a, bh, acc[t], 0, 0, 0);
      if (!BF) {
        bf16x8 bl = as_b8(Wl[idx]);
        acc[t] = __builtin_amdgcn_mfma_f32_16x16x32_bf16(al, bh, acc[t], 0, 0, 0);
        acc[t] = __builtin_amdgcn_mfma_f32_16x16x32_bf16(a,  bl, acc[t], 0, 0, 0);
      }
    }
  }

#pragma unroll
  for (int q = 0; q < 4; ++q) {
    const int row_off = qg * 4 + q;
    const int row = rbase + row_off;
    float xnq = fmaxf(sqrtf(__shfl(xn2, row_off)), MINNORM);
    float s2 = 0.f;
#pragma unroll
    for (int t = 0; t < 8; ++t) { float v = acc[t][q]; s2 += v * v; }
    s2 = rsum16(s2);
    float mxn = fmaxf(sqrtf(s2), MINNORM);
    float r = fast_tanh(mxn * frcp(xnq) * fast_artanh(xnq)) * frcp(mxn);
    float pn = r * mxn;
    if (pn > MAXNORM) { r *= MAXNORM * frcp(pn); pn = MAXNORM; }
    float h[8];
    float hn;
    if (bias_zero) {
#pragma unroll
      for (int t = 0; t < 8; ++t) h[t] = r * acc[t][q];
      hn = pn;
    } else {
      float xy = 0.f;
#pragma unroll
      for (int t = 0; t < 8; ++t) { h[t] = r * acc[t][q]; xy += h[t] * bfr[t]; }
      xy = rsum16(xy);
      float x2 = pn * pn;
      float ca = 1.f + 2.f * xy + y2;
      float cb = 1.f - x2;
      float id = frcp(fmaxf(1.f + 2.f * xy + x2 * y2, MINNORM));
      float s3 = 0.f;
#pragma unroll
      for (int t = 0; t < 8; ++t) { h[t] = (ca * h[t] + cb * bfr[t]) * id; s3 += h[t] * h[t]; }
      hn = fmaxf(sqrtf(rsum16(s3)), MINNORM);
    }
    float ps = (hn > MAXNORM) ? (MAXNORM * frcp(hn)) : 1.f;
    float np = fmaxf(hn * ps, MINNORM);
    float tsc = fast_artanh(np) * frcp(np) * ps;
    if (row < N) {
      u16* xo = xt + (size_t)row * D + lc;
#pragma unroll
      for (int t = 0; t < 8; ++t) xo[16 * t] = f2bf(tsc * h[t]);
    }
  }
}

extern "C" __global__ __launch_bounds__(256)
void OriginHyperbolicGraphConvolution_38628935860614_kernel(
    const void* x, const void* W, const void* b, u16* xt, int N) {
  __shared__ uint4 Wh[2048];   // 32 KB
  __shared__ uint4 Wl[2048];   // 32 KB (fp32 input path only)
  if (detect_bf16((const u32*)x)) k1_body<true >(x, W, b, xt, N, Wh, Wl);
  else                            k1_body<false>(x, W, b, xt, N, Wh, Wl);
}

// ====== ksA: SINGLE edge pass: chunk-local counting sort -> chunk-major ebuck ======
// Merges old ks1a+ks1b: reads ei+ew once, LDS counting-sorts by coarse bucket,
// writes records chunk-major (fully coalesced, no global cursor atomics) plus a
// u16 per-chunk bucket-offset row soffs[c][0..nb] (soffs[c][nb] = valid count).
// Record: x = src(17b) | dstin(7b)<<17, y = w f32 bits.
extern "C" __global__ __launch_bounds__(256) void ksA(
    const int* ei, const void* ew, uint2* ebuck, u16* soffs, int E, int N, int nb) {
  __shared__ int   hist[MAXNB];        // 4 KB
  __shared__ int   sArr[MAXNB + 1];    // 4 KB
  __shared__ int   psum[256];          // 1 KB
  __shared__ uint2 recs[CHUNK];        // 16 KB
  const bool i64 = detect_i64(ei);
  const bool bf  = detect_bf16((const u32*)ew);
  const int tid   = threadIdx.x;
  const int cbase = blockIdx.x * CHUNK;

  for (int i = tid; i < MAXNB; i += 256) hist[i] = 0;
  __syncthreads();

  int bkt[8], rank[8]; u32 px[8], wb[8]; bool val[8];
#pragma unroll
  for (int r = 0; r < 8; ++r) {
    const int e = cbase + r * 256 + tid;
    val[r] = false;
    if (e < E) {
      int dst, src;
      if (i64) { dst = ei[2 * (size_t)e]; src = ei[2 * ((size_t)E + e)]; }
      else     { dst = ei[e];             src = ei[(size_t)E + e]; }
      if ((unsigned)dst < (unsigned)N && (unsigned)src < (unsigned)N) {
        val[r] = true;
        bkt[r] = dst >> BSH;
        px[r]  = (u32)src | ((u32)(dst & ((1 << BSH) - 1)) << 17);
        float w;
        if (bf) w = bf2f(((const u16*)ew)[e]); else w = ((const float*)ew)[e];
        wb[r] = __float_as_uint(w);
        rank[r] = atomicAdd(&hist[bkt[r]], 1);
      }
    }
  }
  __syncthreads();

  // exclusive scan of hist -> sArr (256 threads x 4 bins)
  const int g0 = tid * 4;
  int loc[4], ts = 0;
#pragma unroll
  for (int i = 0; i < 4; ++i) { loc[i] = ts; ts += hist[g0 + i]; }
  psum[tid] = ts; __syncthreads();
#pragma unroll
  for (int off = 1; off < 256; off <<= 1) {
    int t = (tid >= off) ? psum[tid - off] : 0;
    __syncthreads();
    psum[tid] += t;
    __syncthreads();
  }
  const int excl = psum[tid] - ts;
#pragma unroll
  for (int i = 0; i < 4; ++i) sArr[g0 + i] = excl + loc[i];
  if (tid == 255) sArr[MAXNB] = psum[255];
  __syncthreads();

  // place into LDS in bucket-sorted order
#pragma unroll
  for (int r = 0; r < 8; ++r) if (val[r])
    recs[sArr[bkt[r]] + rank[r]] = make_uint2(px[r], wb[r]);
  __syncthreads();

  const int vcnt = sArr[MAXNB];
  // coalesced chunk-major write + per-chunk offset row
  for (int i = tid; i < vcnt; i += 256) ebuck[(size_t)cbase + i] = recs[i];
  u16* so = soffs + (size_t)blockIdx.x * (nb + 1);
  for (int b = tid; b <= nb; b += 256) so[b] = (u16)sArr[b];
}

// ====== ks2sum: per-bucket totals from soffs diffs (soffs is L2-resident) ======
extern "C" __global__ __launch_bounds__(256) void ks2sum(
    const u16* soffs, int* btot, int nb, int nchunks) {
  __shared__ int red[256];
  const int b = blockIdx.x, tid = threadIdx.x;
  int s = 0;
  for (int c = tid; c < nchunks; c += 256) {
    const u16* so = soffs + (size_t)c * (nb + 1) + b;
    s += (int)so[1] - (int)so[0];
  }
  red[tid] = s; __syncthreads();
#pragma unroll
  for (int off = 128; off; off >>= 1) {
    if (tid < off) red[tid] += red[tid + off];
    __syncthreads();
  }
  if (tid == 0) btot[b] = red[0];
}

// ====== ks2scan: bucket bases (nb <= 1024) ======
extern "C" __global__ __launch_bounds__(1024) void ks2scan(
    const int* btot, int* bbase, int nb) {
  __shared__ int sc[1024];
  const int t = threadIdx.x;
  int v = (t < nb) ? btot[t] : 0;
  sc[t] = v; __syncthreads();
#pragma unroll
  for (int off = 1; off < 1024; off <<= 1) {
    int u = (t >= off) ? sc[t - off] : 0;
    __syncthreads();
    sc[t] += u;
    __syncthreads();
  }
  if (t < nb) bbase[t] = sc[t] - v;
  if (t == 1023) bbase[nb] = sc[1023];
}

// ====== ks3: gather bucket's runs -> LDS -> node-sort -> esrt + offs ======
// Block per bucket. Phase 1: 256 threads pull this bucket's ~2.6-record runs
// from all chunks into 48 KB LDS staging (parallel, no dependent chains) while
// node-histogramming. Phase 2: 128-scan -> per-node starts (writes offs).
// Phase 3: scatter LDS -> esrt (16 KB L2-resident window, amp ~1), stripping
// records to plain (src, w). Fallback (bucket > SCAP): two direct passes.
extern "C" __global__ __launch_bounds__(256) void ks3(
    const uint2* ebuck, const u16* soffs, const int* bbase,
    uint2* esrt, int* offs, int N, int nb, int nchunks) {
  __shared__ uint2 stage[SCAP];      // 48 KB
  __shared__ int hist[128], sc[128], cur[128];
  __shared__ int lcur;
  const int tid = threadIdx.x;
  const int b = blockIdx.x;
  const int s0 = bbase[b], s1 = bbase[b + 1], sz = s1 - s0;
  if (tid < 128) hist[tid] = 0;
  if (tid == 0) lcur = 0;
  __syncthreads();

  const bool fit = (sz <= SCAP);
  if (fit) {
    for (int c = tid; c < nchunks; c += 256) {
      const u16* so = soffs + (size_t)c * (nb + 1) + b;
      const int a = so[0], e = so[1];
      if (e > a) {
        const int base = atomicAdd(&lcur, e - a);
        for (int j = a; j < e; ++j) {
          const uint2 r = ebuck[(size_t)c * CHUNK + j];
          stage[base + (j - a)] = r;
          atomicAdd(&hist[(r.x >> 17) & 127], 1);
        }
      }
    }
  } else {
    for (int c = tid; c < nchunks; c += 256) {
      const u16* so = soffs + (size_t)c * (nb + 1) + b;
      for (int j = so[0]; j < so[1]; ++j)
        atomicAdd(&hist[(ebuck[(size_t)c * CHUNK + j].x >> 17) & 127], 1);
    }
  }
  __syncthreads();

  int v = 0;
  if (tid < 128) { v = hist[tid]; sc[tid] = v; }
  __syncthreads();
#pragma unroll
  for (int off = 1; off < 128; off <<= 1) {
    int t = (tid < 128 && tid >= off) ? sc[tid - off] : 0;
    __syncthreads();
    if (tid < 128) sc[tid] += t;
    __syncthreads();
  }
  if (tid < 128) {
    const int st = sc[tid] - v;
    cur[tid] = st;
    const int node = (b << BSH) + tid;
    if (node < N) offs[node] = s0 + st;
  }
  if (tid == 0 && b == nb - 1) offs[N] = s1;
  __syncthreads();

  if (fit) {
    for (int i = tid; i < sz; i += 256) {
      const uint2 r = stage[i];
      const int d = atomicAdd(&cur[(r.x >> 17) & 127], 1);
      esrt[s0 + d] = make_uint2(r.x & 0x1FFFFu, r.y);
    }
  } else {
    for (int c = tid; c < nchunks; c += 256) {
      const u16* so = soffs + (size_t)c * (nb + 1) + b;
      for (int j = so[0]; j < so[1]; ++j) {
        const uint2 r = ebuck[(size_t)c * CHUNK + j];
        const int d = atomicAdd(&cur[(r.x >> 17) & 127], 1);
        esrt[s0 + d] = make_uint2(r.x & 0x1FFFFu, r.y);
      }
    }
  }
}

// ====== kagg: gather-aggregate per node + fused finalize ======
// Wave per node, register accumulation. Edge segment is wave-uniform: after
// readfirstlane, each edge record is ONE uniform load (L1-hit line broadcast,
// likely s_load) — no cooperative chunk load, no ds_bpermute. Gathers 8-deep.
extern "C" __global__ __launch_bounds__(256) void kagg(
    const int* offs, const uint2* esrt, const u16* xt,
    void* out, const void* xdet, int N) {
  const bool bf = detect_bf16((const u32*)xdet);
  const int lane = threadIdx.x & 63;
  const int node = blockIdx.x * 4 + (threadIdx.x >> 6);
  if (node >= N) return;
  int s0 = __builtin_amdgcn_readfirstlane(offs[node]);
  int s1 = __builtin_amdgcn_readfirstlane(offs[node + 1]);
  const uint2* ep = esrt + s0;
  const int cnt = s1 - s0;
  const u32* xtw = (const u32*)xt;
  float a0 = 0.f, a1 = 0.f;
  int i = 0;
  for (; i + 8 <= cnt; i += 8) {
    uint2 e[8]; u32 u[8];
#pragma unroll
    for (int k = 0; k < 8; ++k) e[k] = ep[i + k];          // uniform loads
#pragma unroll
    for (int k = 0; k < 8; ++k) u[k] = xtw[(e[k].x << 6) | lane];  // 8 gathers in flight
#pragma unroll
    for (int k = 0; k < 8; ++k) {
      const float w = __uint_as_float(e[k].y);
      a0 += w * bflo(u[k]);
      a1 += w * bfhi(u[k]);
    }
  }
  for (; i + 4 <= cnt; i += 4) {
    uint2 e[4]; u32 u[4];
#pragma unroll
    for (int k = 0; k < 4; ++k) e[k] = ep[i + k];
#pragma unroll
    for (int k = 0; k < 4; ++k) u[k] = xtw[(e[k].x << 6) | lane];
#pragma unroll
    for (int k = 0; k < 4; ++k) {
      const float w = __uint_as_float(e[k].y);
      a0 += w * bflo(u[k]);
      a1 += w * bfhi(u[k]);
    }
  }
  for (; i < cnt; ++i) {
    const uint2 e = ep[i];
    const u32 u = xtw[(e.x << 6) | lane];
    const float w = __uint_as_float(e.y);
    a0 += w * bflo(u);
    a1 += w * bfhi(u);
  }
  // finalize: expmap0 -> proj -> logmap0 -> relu -> expmap0 -> proj
  float n = fmaxf(sqrtf(wsum(a0 * a0 + a1 * a1)), MINNORM);
  float tn = fast_tanh(n);
  float m = tn * frcp(n);
  if (tn > MAXNORM) { m *= MAXNORM * frcp(tn); tn = MAXNORM; }
  float nn = fmaxf(tn, MINNORM);
  m *= fast_artanh(nn) * frcp(nn);
  float tA = fmaxf(m * a0, 0.f), tB = fmaxf(m * a1, 0.f);
  float nr = fmaxf(sqrtf(wsum(tA * tA + tB * tB)), MINNORM);
  float t2 = fast_tanh(nr);
  float m2 = t2 * frcp(nr);
  if (t2 > MAXNORM) m2 *= MAXNORM * frcp(t2);
  float oA = m2 * tA, oB = m2 * tB;
  if (bf) {
    u32 o = ((u32)f2bf(oA)) | (((u32)f2bf(oB)) << 16);
    ((u32*)out)[(size_t)node * 64 + lane] = o;
  } else {
    ((float2*)out)[(size_t)node * 64 + lane] = make_float2(oA, oB);
  }
}

extern "C" void kernel_launch(void* const* d_in, const int* in_sizes, int n_in,
                              void* d_out, int out_size, void* d_ws, size_t ws_size,
                              hipStream_t stream) {
  const void* x    = d_in[0];
  const void* W    = d_in[1];
  const void* bias = d_in[2];
  const int*  ei   = (const int*)d_in[3];
  const void* ew   = d_in[4];
  const int N = in_sizes[0] / D;
  const int E = in_sizes[4];
  const int nchunks = (E + CHUNK - 1) / CHUNK;
  const int nb      = (N + (1 << BSH) - 1) >> BSH;

  char* ws = (char*)d_ws;
  size_t off = 0;
  auto carve = [&](size_t bytes) { char* p = ws + off; off = (off + bytes + 255) & ~(size_t)255; return p; };
  u16*   xt     = (u16*)  carve((size_t)N * D * sizeof(u16));              // 25.6 MB
  uint2* ebuck  = (uint2*)carve((size_t)nchunks * CHUNK * sizeof(uint2));  // 12.8 MB
  uint2* esrt   = (uint2*)carve((size_t)E * sizeof(uint2));                // 12.8 MB
  u16*   soffs  = (u16*)  carve((size_t)nchunks * (nb + 1) * sizeof(u16)); // 1.2 MB
  int*   btot   = (int*)  carve((size_t)nb * sizeof(int));
  int*   bbase  = (int*)  carve((size_t)(nb + 1) * sizeof(int));
  int*   offs   = (int*)  carve((size_t)(N + 1) * sizeof(int));            // 0.4 MB

  OriginHyperbolicGraphConvolution_38628935860614_kernel<<<(N + 63) / 64, 256, 0, stream>>>(
      x, W, bias, xt, N);
  ksA   <<<nchunks, 256, 0, stream>>>(ei, ew, ebuck, soffs, E, N, nb);
  ks2sum<<<nb, 256, 0, stream>>>(soffs, btot, nb, nchunks);
  ks2scan<<<1, 1024, 0, stream>>>(btot, bbase, nb);
  ks3   <<<nb, 256, 0, stream>>>(ebuck, soffs, bbase, esrt, offs, N, nb, nchunks);
  kagg  <<<(N + 3) / 4, 256, 0, stream>>>(offs, esrt, xt, d_out, x, N);
}